// Round 6
// baseline (147.594 us; speedup 1.0000x reference)
//
#include <hip/hip_runtime.h>
#include <math.h>

// Problem constants (fixed by the reference)
#define NNODES 20000
#define NEDGES 320000
#define FIN    512
#define HIDD   128
#define OUTD   128
#define NH     4
#define NC     64
#define HC     256   // NH*NC

typedef short bf16x8 __attribute__((ext_vector_type(8)));
typedef float f32x4  __attribute__((ext_vector_type(4)));

__device__ __forceinline__ unsigned short f2bf(float f) {
    unsigned int u = __float_as_uint(f);
    unsigned int r = 0x7fffu + ((u >> 16) & 1u);
    return (unsigned short)((u + r) >> 16);
}
__device__ __forceinline__ float b2f(short t) {
    return __uint_as_float(((unsigned)(unsigned short)t) << 16);
}
__device__ __forceinline__ float4 f4max(float4 a, float4 b) {
    return make_float4(fmaxf(a.x,b.x), fmaxf(a.y,b.y), fmaxf(a.z,b.z), fmaxf(a.w,b.w));
}
__device__ __forceinline__ float4 f4add(float4 a, float4 b) {
    return make_float4(a.x+b.x, a.y+b.y, a.z+b.z, a.w+b.w);
}
__device__ __forceinline__ float4 f4sub(float4 a, float4 b) {
    return make_float4(a.x-b.x, a.y-b.y, a.z-b.z, a.w-b.w);
}
__device__ __forceinline__ float4 f4mul(float4 a, float4 b) {
    return make_float4(a.x*b.x, a.y*b.y, a.z*b.z, a.w*b.w);
}
__device__ __forceinline__ float4 f4exp(float4 a) {
    return make_float4(__expf(a.x), __expf(a.y), __expf(a.z), __expf(a.w));
}
__device__ __forceinline__ float4 shflx4(float4 v, int m) {
    return make_float4(__shfl_xor(v.x,m), __shfl_xor(v.y,m), __shfl_xor(v.z,m), __shfl_xor(v.w,m));
}

// ---------------------------------------------------------------------------
// Prep (role-split blocks):
//   blocks [0,64):    W1 transpose-cast via LDS tile (coalesced both sides)
//   blocks [64,192):  W2@Wg fuse -> W2gt bf16 + b2g
//   blocks [192,271): deg init (=1 self loop)
// ---------------------------------------------------------------------------
#define PREP_TB1 64
#define PREP_TB2 192
__global__ __launch_bounds__(256)
void prep_kernel(const float* __restrict__ W1, unsigned short* __restrict__ W1t,
                 const float* __restrict__ W2, const float* __restrict__ b2,
                 const float* __restrict__ Wg, unsigned short* __restrict__ W2gt,
                 float* __restrict__ b2g, int* __restrict__ deg, int n) {
    const int bid = blockIdx.x;
    const int tid = threadIdx.x;
    if (bid < PREP_TB1) {
        // 32x32 tile transpose: W1 [512][128] fp32 -> W1t [128][512] bf16
        __shared__ float tile[32][33];
        const int tk = bid >> 2;             // 0..15 (k tiles)
        const int tn = bid & 3;              // 0..3  (n tiles)
        const int k0 = tk * 32, n0 = tn * 32;
        const int nin = tid & 31;
        const int r8  = tid >> 5;            // 0..7
        #pragma unroll
        for (int s = 0; s < 4; ++s) {
            int k = s * 8 + r8;
            tile[k][nin] = W1[(size_t)(k0 + k) * HIDD + n0 + nin];
        }
        __syncthreads();
        #pragma unroll
        for (int s = 0; s < 4; ++s) {
            int nn = s * 8 + r8;
            W1t[(size_t)(n0 + nn) * FIN + k0 + nin] = f2bf(tile[nin][nn]);
        }
    } else if (bid < PREP_TB2) {
        int local = (bid - PREP_TB1) * 256 + tid;   // 0..32767
        int nn = local >> 7;         // 0..255 output col
        int k  = local & 127;        // 0..127 input row
        float s = 0.f;
        #pragma unroll 8
        for (int t = 0; t < HIDD; ++t)
            s += W2[(size_t)k * OUTD + t] * Wg[(size_t)t * HC + nn];
        W2gt[(size_t)nn * HIDD + k] = f2bf(s);
        if (k == 0) {
            float t2 = 0.f;
            #pragma unroll 8
            for (int t = 0; t < OUTD; ++t) t2 += b2[t] * Wg[(size_t)t * HC + nn];
            b2g[nn] = t2;
        }
    } else {
        int i = (bid - PREP_TB2) * 256 + tid;
        if (i < n) deg[i] = 1;      // self loop
    }
}

// ---------------------------------------------------------------------------
// GEMM1 (+ fused degree count): h1 = relu(x @ W1t^T + b1)  [bf16 out]
//   BM=32, BN=128(=N), BK=64; 4 waves (2x2); XOR-swizzled LDS.
//   Blocks >= gemmBlocks do the edge-degree atomic count (overlapped).
// ---------------------------------------------------------------------------
__global__ __launch_bounds__(256)
void gemm1_count_kernel(const float* __restrict__ A,            // x [M][512] fp32
                        const unsigned short* __restrict__ Bt,  // W1t [128][512]
                        const float* __restrict__ bias,         // b1
                        unsigned short* __restrict__ C,         // h1 [M][128]
                        const int* __restrict__ dst, int* __restrict__ deg,
                        int M, int E, int gemmBlocks) {
    __shared__ unsigned short As[32 * 64];    // 4 KB
    __shared__ unsigned short Bs[128 * 64];   // 16 KB

    if ((int)blockIdx.x >= gemmBlocks) {
        int i = ((int)blockIdx.x - gemmBlocks) * 256 + threadIdx.x;
        if (i < E) atomicAdd(&deg[dst[i]], 1);
        return;
    }

    const int tid  = threadIdx.x;
    const int lane = tid & 63;
    const int w    = tid >> 6;
    const int wr   = w >> 1;
    const int wc   = w & 1;
    const int m0   = blockIdx.x * 32;

    char* pA = (char*)As;
    char* pB = (char*)Bs;

    f32x4 acc[4];
    #pragma unroll
    for (int n = 0; n < 4; ++n) acc[n] = (f32x4){0.f, 0.f, 0.f, 0.f};

    for (int k0 = 0; k0 < FIN; k0 += 64) {
        {
            const int row = tid >> 3;                // 0..31
            const int sg  = tid & 7;                 // 8-float segment
            const bool ok = (m0 + row) < M;
            const float4* Ap = (const float4*)(A + (size_t)(m0 + row) * FIN + k0 + sg * 8);
            float4 f0 = make_float4(0,0,0,0), f1 = f0;
            if (ok) { f0 = Ap[0]; f1 = Ap[1]; }
            unsigned short u[8];
            u[0]=f2bf(f0.x); u[1]=f2bf(f0.y); u[2]=f2bf(f0.z); u[3]=f2bf(f0.w);
            u[4]=f2bf(f1.x); u[5]=f2bf(f1.y); u[6]=f2bf(f1.z); u[7]=f2bf(f1.w);
            *(bf16x8*)(pA + (((row * 128 + sg * 16)) ^ ((row & 7) << 4))) = *(bf16x8*)&u[0];
        }
        #pragma unroll
        for (int i = 0; i < 4; ++i) {
            int s   = tid + i * 256;
            int col = s >> 3;
            int sg  = s & 7;
            bf16x8 v = *(const bf16x8*)(Bt + (size_t)col * FIN + k0 + sg * 8);
            *(bf16x8*)(pB + (((col * 128 + sg * 16)) ^ ((col & 7) << 4))) = v;
        }
        __syncthreads();

        #pragma unroll
        for (int ks = 0; ks < 2; ++ks) {
            const int kb = ks * 64 + ((lane >> 4) << 4);
            int row = wr * 16 + (lane & 15);
            bf16x8 a = *(const bf16x8*)(pA + ((row * 128 + kb) ^ ((row & 7) << 4)));
            bf16x8 b[4];
            #pragma unroll
            for (int n = 0; n < 4; ++n) {
                int col = wc * 64 + n * 16 + (lane & 15);
                b[n] = *(const bf16x8*)(pB + ((col * 128 + kb) ^ ((col & 7) << 4)));
            }
            #pragma unroll
            for (int n = 0; n < 4; ++n)
                acc[n] = __builtin_amdgcn_mfma_f32_16x16x32_bf16(a, b[n], acc[n], 0, 0, 0);
        }
        __syncthreads();
    }

    #pragma unroll
    for (int n = 0; n < 4; ++n) {
        const int col = wc * 64 + n * 16 + (lane & 15);
        const float bv = bias[col];
        #pragma unroll
        for (int r = 0; r < 4; ++r) {
            const int row = m0 + wr * 16 + ((lane >> 4) << 2) + r;
            if (row >= M) continue;
            float v = fmaxf(acc[n][r] + bv, 0.f);
            C[(size_t)row * HIDD + col] = f2bf(v);
        }
    }
}

// ---------------------------------------------------------------------------
// GEMM2 (+ fused attention dots + fused CSR scan):
//   xgb = h1 @ W2gt^T + b2g [bf16], a_src/a_dst dots in the epilogue.
//   Block (gemmX, 0) runs the offset scan instead (deg is final: this kernel
//   launches after gemm1_count completes). Scan also reserves the self-loop
//   slot: csr[offs[i]] = i, cursor[i] = offs[i]+1.
// ---------------------------------------------------------------------------
__global__ __launch_bounds__(256)
void gemm2_dots_scan_kernel(const unsigned short* __restrict__ Ab,   // h1 [M][128]
                            const unsigned short* __restrict__ Bt,   // W2gt [256][128]
                            const float* __restrict__ b2g,           // [256]
                            const float* __restrict__ att_src,       // [4][64]
                            const float* __restrict__ att_dst,       // [4][64]
                            unsigned short* __restrict__ xgb,        // [M][256]
                            float* __restrict__ a_src, float* __restrict__ a_dst,
                            const int* __restrict__ deg, int* __restrict__ offs,
                            int* __restrict__ cursor, int* __restrict__ csr,
                            int M, int gemmX) {
    const int tid  = threadIdx.x;

    if ((int)blockIdx.x == gemmX) {
        if (blockIdx.y != 0) return;
        // ---- 256-thread chunked scan with carry ----
        __shared__ int wsum_s[4];
        __shared__ int carry_s;
        const int lane = tid & 63;
        const int wv   = tid >> 6;
        if (tid == 0) carry_s = 0;
        __syncthreads();
        for (int c0 = 0; c0 < M; c0 += 256) {
            int i = c0 + tid;
            int v = (i < M) ? deg[i] : 0;
            int s = v;
            #pragma unroll
            for (int d = 1; d < 64; d <<= 1) {
                int t = __shfl_up(s, d);
                if (lane >= d) s += t;
            }
            if (lane == 63) wsum_s[wv] = s;
            __syncthreads();
            int base = carry_s;
            int wpre = 0;
            #pragma unroll
            for (int t = 0; t < 4; ++t) if (t < wv) wpre += wsum_s[t];
            int excl = base + wpre + s - v;
            if (i < M) {
                offs[i]   = excl;
                cursor[i] = excl + 1;   // slot 0 reserved for self loop
                csr[excl] = i;
            }
            __syncthreads();
            if (tid == 255) carry_s = base + wpre + s;
            __syncthreads();
        }
        if (tid == 0) offs[M] = carry_s;
        return;
    }

    __shared__ unsigned short As[64 * 64];    // 8 KB
    __shared__ unsigned short Bs[128 * 64];   // 16 KB

    const int lane = tid & 63;
    const int w    = tid >> 6;
    const int wr   = w >> 1;
    const int wc   = w & 1;
    const int m0   = blockIdx.x * 64;
    const int n0   = blockIdx.y * 128;

    char* pA = (char*)As;
    char* pB = (char*)Bs;

    f32x4 acc[2][4];
    #pragma unroll
    for (int m = 0; m < 2; ++m)
        #pragma unroll
        for (int n = 0; n < 4; ++n) acc[m][n] = (f32x4){0.f, 0.f, 0.f, 0.f};

    for (int k0 = 0; k0 < HIDD; k0 += 64) {
        #pragma unroll
        for (int i = 0; i < 2; ++i) {
            int s   = tid + i * 256;
            int row = s >> 3;
            int sg  = s & 7;
            bf16x8 v = {};
            if ((m0 + row) < M)
                v = *(const bf16x8*)(Ab + (size_t)(m0 + row) * HIDD + k0 + sg * 8);
            *(bf16x8*)(pA + (((row * 128 + sg * 16)) ^ ((row & 7) << 4))) = v;
        }
        #pragma unroll
        for (int i = 0; i < 4; ++i) {
            int s   = tid + i * 256;
            int col = s >> 3;
            int sg  = s & 7;
            bf16x8 v = *(const bf16x8*)(Bt + (size_t)(n0 + col) * HIDD + k0 + sg * 8);
            *(bf16x8*)(pB + (((col * 128 + sg * 16)) ^ ((col & 7) << 4))) = v;
        }
        __syncthreads();

        #pragma unroll
        for (int ks = 0; ks < 2; ++ks) {
            const int kb = ks * 64 + ((lane >> 4) << 4);
            bf16x8 a[2], b[4];
            #pragma unroll
            for (int m = 0; m < 2; ++m) {
                int row = wr * 32 + m * 16 + (lane & 15);
                a[m] = *(const bf16x8*)(pA + ((row * 128 + kb) ^ ((row & 7) << 4)));
            }
            #pragma unroll
            for (int n = 0; n < 4; ++n) {
                int col = wc * 64 + n * 16 + (lane & 15);
                b[n] = *(const bf16x8*)(pB + ((col * 128 + kb) ^ ((col & 7) << 4)));
            }
            #pragma unroll
            for (int m = 0; m < 2; ++m)
                #pragma unroll
                for (int n = 0; n < 4; ++n)
                    acc[m][n] = __builtin_amdgcn_mfma_f32_16x16x32_bf16(
                        a[m], b[n], acc[m][n], 0, 0, 0);
        }
        __syncthreads();
    }

    // ---- epilogue: store xgb + per-head attention dots ----
    const int head = blockIdx.y * 2 + wc;            // 0..3
    const int cIn  = lane & 15;
    float ds_p[2][4], dd_p[2][4];
    #pragma unroll
    for (int m = 0; m < 2; ++m)
        #pragma unroll
        for (int r = 0; r < 4; ++r) { ds_p[m][r] = 0.f; dd_p[m][r] = 0.f; }

    #pragma unroll
    for (int n = 0; n < 4; ++n) {
        const int ch  = n * 16 + cIn;                // channel within head
        const int col = n0 + wc * 64 + n * 16 + cIn;
        const float bv   = b2g[col];
        const float as_c = att_src[head * NC + ch];
        const float ad_c = att_dst[head * NC + ch];
        #pragma unroll
        for (int m = 0; m < 2; ++m) {
            #pragma unroll
            for (int r = 0; r < 4; ++r) {
                const int row = m0 + wr * 32 + m * 16 + ((lane >> 4) << 2) + r;
                float v = acc[m][n][r] + bv;
                if (row < M) xgb[(size_t)row * HC + col] = f2bf(v);
                ds_p[m][r] += v * as_c;
                dd_p[m][r] += v * ad_c;
            }
        }
    }
    #pragma unroll
    for (int m = 0; m < 2; ++m) {
        #pragma unroll
        for (int r = 0; r < 4; ++r) {
            float s = ds_p[m][r], d = dd_p[m][r];
            s += __shfl_xor(s, 1); s += __shfl_xor(s, 2);
            s += __shfl_xor(s, 4); s += __shfl_xor(s, 8);
            d += __shfl_xor(d, 1); d += __shfl_xor(d, 2);
            d += __shfl_xor(d, 4); d += __shfl_xor(d, 8);
            if (cIn == 0) {
                const int row = m0 + wr * 32 + m * 16 + ((lane >> 4) << 2) + r;
                if (row < M) {
                    a_src[row * NH + head] = s;
                    a_dst[row * NH + head] = d;
                }
            }
        }
    }
}

// ---------------------------------------------------------------------------
// Scatter real edges into CSR slots (self-loops pre-placed by the scan)
// ---------------------------------------------------------------------------
__global__ void scatter_kernel(const int* __restrict__ src, const int* __restrict__ dst,
                               int* __restrict__ cursor, int* __restrict__ csr_src,
                               int e) {
    int i = blockIdx.x * 256 + threadIdx.x;
    if (i < e) {
        int s = src[i], d = dst[i];
        csr_src[atomicAdd(&cursor[d], 1)] = s;
    }
}

// ---------------------------------------------------------------------------
// Aggregation v4: one wave per node.
// Pass A: lane-parallel softmax; logits from asrc gather (L2-resident) +
//         wave-uniform adst; exp/src cached in LDS.
// Pass B: half-wave channel split; 16-edge unroll (8 gathers in flight/lane).
// ---------------------------------------------------------------------------
__global__ __launch_bounds__(256)
void gat_aggregate4_kernel(const unsigned short* __restrict__ xgb,
                           const float4* __restrict__ asrc4,
                           const float4* __restrict__ adst4,
                           const int* __restrict__ offs, const int* __restrict__ csr_src,
                           const float* __restrict__ bias, float* __restrict__ out, int n) {
    __shared__ float4 exbuf[4][64];
    __shared__ int    sbuf[4][64];
    const int wv   = threadIdx.x >> 6;
    const int lane = threadIdx.x & 63;
    const int node = blockIdx.x * 4 + wv;
    if (node >= n) return;
    const int beg = offs[node], end = offs[node + 1];
    const int deg = end - beg;
    const float4 adstv = adst4[node];

    // ---- pass A ----
    float4 m   = make_float4(-INFINITY, -INFINITY, -INFINITY, -INFINITY);
    float4 den = make_float4(0.f, 0.f, 0.f, 0.f);
    for (int c0 = 0; c0 < deg; c0 += 64) {
        int idx = beg + c0 + lane;
        bool ok = idx < end;
        int s = ok ? csr_src[idx] : 0;
        float4 e = make_float4(-INFINITY, -INFINITY, -INFINITY, -INFINITY);
        if (ok) {
            float4 a = asrc4[s];
            e = f4add(a, adstv);
            e.x = e.x > 0.f ? e.x : 0.2f * e.x;
            e.y = e.y > 0.f ? e.y : 0.2f * e.y;
            e.z = e.z > 0.f ? e.z : 0.2f * e.z;
            e.w = e.w > 0.f ? e.w : 0.2f * e.w;
        }
        float4 cm = e;
        #pragma unroll
        for (int dd = 32; dd >= 1; dd >>= 1) cm = f4max(cm, shflx4(cm, dd));
        float4 nm = f4max(m, cm);
        float4 ex = f4exp(f4sub(e, nm));      // masked lanes: exp(-inf)=0
        exbuf[wv][lane] = ex;
        sbuf[wv][lane]  = s;
        float4 cs = ex;
        #pragma unroll
        for (int dd = 32; dd >= 1; dd >>= 1) cs = f4add(cs, shflx4(cs, dd));
        den = f4add(f4mul(den, f4exp(f4sub(m, nm))), cs);
        m = nm;
    }

    const int hi = lane >> 5;
    const int ll = lane & 31;       // owns channels 8*ll .. 8*ll+7
    const int h  = ll >> 3;
    const float denh = (h == 0) ? den.x : (h == 1) ? den.y : (h == 2) ? den.z : den.w;
    const float inv = 1.f / (denh + 1e-16f);

    float4 acc0 = make_float4(0.f, 0.f, 0.f, 0.f);
    float4 acc1 = make_float4(0.f, 0.f, 0.f, 0.f);
    const float* exf = (const float*)&exbuf[wv][0];

    auto do_edge = [&](int jj) {
        int s = sbuf[wv][jj];
        float wgt = exf[jj * 4 + h];
        bf16x8 v = *(const bf16x8*)(xgb + (size_t)s * HC + ll * 8);
        acc0.x += wgt * b2f(v[0]); acc0.y += wgt * b2f(v[1]);
        acc0.z += wgt * b2f(v[2]); acc0.w += wgt * b2f(v[3]);
        acc1.x += wgt * b2f(v[4]); acc1.y += wgt * b2f(v[5]);
        acc1.z += wgt * b2f(v[6]); acc1.w += wgt * b2f(v[7]);
    };

    auto run_chunk = [&](int cn) {
        int j = 0;
        for (; j + 16 <= cn; j += 16) {
            int ss[8]; float ww[8]; bf16x8 vv[8];
            #pragma unroll
            for (int t = 0; t < 8; ++t) {
                int jj = j + 2 * t + hi;
                ss[t] = sbuf[wv][jj];
                ww[t] = exf[jj * 4 + h];
            }
            #pragma unroll
            for (int t = 0; t < 8; ++t)
                vv[t] = *(const bf16x8*)(xgb + (size_t)ss[t] * HC + ll * 8);
            #pragma unroll
            for (int t = 0; t < 8; ++t) {
                acc0.x += ww[t]*b2f(vv[t][0]); acc0.y += ww[t]*b2f(vv[t][1]);
                acc0.z += ww[t]*b2f(vv[t][2]); acc0.w += ww[t]*b2f(vv[t][3]);
                acc1.x += ww[t]*b2f(vv[t][4]); acc1.y += ww[t]*b2f(vv[t][5]);
                acc1.z += ww[t]*b2f(vv[t][6]); acc1.w += ww[t]*b2f(vv[t][7]);
            }
        }
        for (; j + 8 <= cn; j += 8) {
            do_edge(j + hi);     do_edge(j + 2 + hi);
            do_edge(j + 4 + hi); do_edge(j + 6 + hi);
        }
        for (; j + 4 <= cn; j += 4) {
            do_edge(j + hi);
            do_edge(j + 2 + hi);
        }
        for (; j < cn; j += 2) {
            int jj = j + hi;
            if (jj < cn) do_edge(jj);
        }
    };

    if (deg <= 64) {
        run_chunk(deg);
    } else {
        for (int c0 = 0; c0 < deg; c0 += 64) {
            int idx = beg + c0 + lane;
            if (idx < end) {
                int s = csr_src[idx];
                float4 e = f4add(asrc4[s], adstv);
                e.x = e.x > 0.f ? e.x : 0.2f * e.x;
                e.y = e.y > 0.f ? e.y : 0.2f * e.y;
                e.z = e.z > 0.f ? e.z : 0.2f * e.z;
                e.w = e.w > 0.f ? e.w : 0.2f * e.w;
                exbuf[wv][lane] = f4exp(f4sub(e, m));
                sbuf[wv][lane]  = s;
            }
            int cn = deg - c0; if (cn > 64) cn = 64;
            run_chunk(cn);
        }
    }

    // combine half-wave partials
    acc0.x += __shfl_xor(acc0.x, 32); acc0.y += __shfl_xor(acc0.y, 32);
    acc0.z += __shfl_xor(acc0.z, 32); acc0.w += __shfl_xor(acc0.w, 32);
    acc1.x += __shfl_xor(acc1.x, 32); acc1.y += __shfl_xor(acc1.y, 32);
    acc1.z += __shfl_xor(acc1.z, 32); acc1.w += __shfl_xor(acc1.w, 32);

    const float4* b4 = (const float4*)bias;
    float4* op = (float4*)(out + (size_t)node * HC);
    if (hi == 0) {
        float4 bv = b4[ll * 2];
        op[ll * 2] = make_float4(acc0.x * inv + bv.x, acc0.y * inv + bv.y,
                                 acc0.z * inv + bv.z, acc0.w * inv + bv.w);
    } else {
        float4 bv = b4[ll * 2 + 1];
        op[ll * 2 + 1] = make_float4(acc1.x * inv + bv.x, acc1.y * inv + bv.y,
                                     acc1.z * inv + bv.z, acc1.w * inv + bv.w);
    }
}

// ---------------------------------------------------------------------------
extern "C" void kernel_launch(void* const* d_in, const int* in_sizes, int n_in,
                              void* d_out, int out_size, void* d_ws, size_t ws_size,
                              hipStream_t stream) {
    const float* x       = (const float*)d_in[0];
    const int*   ei      = (const int*)d_in[1];
    const float* W1      = (const float*)d_in[2];
    const float* b1      = (const float*)d_in[3];
    const float* W2      = (const float*)d_in[4];
    const float* b2      = (const float*)d_in[5];
    const float* Wg      = (const float*)d_in[6];
    const float* att_src = (const float*)d_in[7];
    const float* att_dst = (const float*)d_in[8];
    const float* bias_g  = (const float*)d_in[9];

    const int Nn = in_sizes[0] / FIN;       // 20000
    const int E  = in_sizes[1] / 2;         // 320000
    const int* e_src = ei;
    const int* e_dst = ei + E;

    char* w = (char*)d_ws;
    auto alloc = [&](size_t bytes) { char* p = w; w += (bytes + 255) & ~(size_t)255; return p; };
    unsigned short* W1t  = (unsigned short*)alloc((size_t)OUTD * FIN * 2);
    unsigned short* W2gt = (unsigned short*)alloc((size_t)HC * HIDD * 2);
    float* b2g  = (float*)alloc(HC * 4);
    unsigned short* h1  = (unsigned short*)alloc((size_t)Nn * HIDD * 2);
    unsigned short* xgb = (unsigned short*)alloc((size_t)Nn * HC * 2);
    float* asrc = (float*)alloc((size_t)Nn * NH * 4);
    float* adst = (float*)alloc((size_t)Nn * NH * 4);
    int* deg    = (int*)alloc((size_t)Nn * 4);
    int* offs   = (int*)alloc((size_t)(Nn + 1) * 4);
    int* cursor = (int*)alloc((size_t)Nn * 4);
    int* csr    = (int*)alloc((size_t)(E + Nn) * 4);

    dim3 blk(256);

    // 1) prep: W1t transpose (LDS tiles) | W2gt+b2g | deg=1
    {
        int nb = PREP_TB2 + (Nn + 255) / 256;       // 64 + 128 + 79
        prep_kernel<<<dim3(nb), blk, 0, stream>>>(
            W1, W1t, W2, b2, Wg, W2gt, b2g, deg, Nn);
    }

    // 2) h1 = relu(x@W1 + b1)  [bf16]  + fused degree count
    {
        int gb = (Nn + 31) / 32;                 // 625 gemm blocks
        int cb = (E + 255) / 256;                // 1250 count blocks
        gemm1_count_kernel<<<dim3(gb + cb), blk, 0, stream>>>(
            x, W1t, b1, h1, e_dst, deg, Nn, E, gb);
    }

    // 3) xg = h1 @ W2g + b2g [bf16] + fused attention dots + fused scan
    {
        int gx = (Nn + 63) / 64;                 // 313 gemm x-blocks
        gemm2_dots_scan_kernel<<<dim3(gx + 1, 2), blk, 0, stream>>>(
            h1, W2gt, b2g, att_src, att_dst, xgb, asrc, adst,
            deg, offs, cursor, csr, Nn, gx);
    }

    // 4) scatter real edges (self-loops already placed)
    scatter_kernel<<<dim3((E + 255) / 256), blk, 0, stream>>>(
        e_src, e_dst, cursor, csr, E);

    // 5) softmax + aggregation
    gat_aggregate4_kernel<<<dim3((Nn + 3) / 4), blk, 0, stream>>>(
        xgb, (const float4*)asrc, (const float4*)adst, offs, csr, bias_g,
        (float*)d_out, Nn);
}

// Round 7
// 135.830 us; speedup vs baseline: 1.0866x; 1.0866x over previous
//
#include <hip/hip_runtime.h>
#include <math.h>

// Problem constants (fixed by the reference)
#define NNODES 20000
#define NEDGES 320000
#define FIN    512
#define HIDD   128
#define OUTD   128
#define NH     4
#define NC     64
#define HC     256   // NH*NC

typedef short bf16x8 __attribute__((ext_vector_type(8)));
typedef float f32x4  __attribute__((ext_vector_type(4)));

__device__ __forceinline__ unsigned short f2bf(float f) {
    unsigned int u = __float_as_uint(f);
    unsigned int r = 0x7fffu + ((u >> 16) & 1u);
    return (unsigned short)((u + r) >> 16);
}
__device__ __forceinline__ float b2f(short t) {
    return __uint_as_float(((unsigned)(unsigned short)t) << 16);
}
__device__ __forceinline__ float4 f4max(float4 a, float4 b) {
    return make_float4(fmaxf(a.x,b.x), fmaxf(a.y,b.y), fmaxf(a.z,b.z), fmaxf(a.w,b.w));
}
__device__ __forceinline__ float4 f4add(float4 a, float4 b) {
    return make_float4(a.x+b.x, a.y+b.y, a.z+b.z, a.w+b.w);
}
__device__ __forceinline__ float4 f4sub(float4 a, float4 b) {
    return make_float4(a.x-b.x, a.y-b.y, a.z-b.z, a.w-b.w);
}
__device__ __forceinline__ float4 f4mul(float4 a, float4 b) {
    return make_float4(a.x*b.x, a.y*b.y, a.z*b.z, a.w*b.w);
}
__device__ __forceinline__ float4 f4exp(float4 a) {
    return make_float4(__expf(a.x), __expf(a.y), __expf(a.z), __expf(a.w));
}
__device__ __forceinline__ float4 shflx4(float4 v, int m) {
    return make_float4(__shfl_xor(v.x,m), __shfl_xor(v.y,m), __shfl_xor(v.z,m), __shfl_xor(v.w,m));
}

// ---------------------------------------------------------------------------
// Prep (role-split blocks):
//   blocks [0,64):    W1 transpose-cast via LDS tile (coalesced both sides)
//   blocks [64,192):  W2@Wg fuse -> W2gt bf16 + b2g
//   blocks [192,...): deg init (=1 self loop)
// ---------------------------------------------------------------------------
#define PREP_TB1 64
#define PREP_TB2 192
__global__ __launch_bounds__(256)
void prep_kernel(const float* __restrict__ W1, unsigned short* __restrict__ W1t,
                 const float* __restrict__ W2, const float* __restrict__ b2,
                 const float* __restrict__ Wg, unsigned short* __restrict__ W2gt,
                 float* __restrict__ b2g, int* __restrict__ deg, int n) {
    const int bid = blockIdx.x;
    const int tid = threadIdx.x;
    if (bid < PREP_TB1) {
        // 32x32 tile transpose: W1 [512][128] fp32 -> W1t [128][512] bf16
        __shared__ float tile[32][33];
        const int tk = bid >> 2;             // 0..15 (k tiles)
        const int tn = bid & 3;              // 0..3  (n tiles)
        const int k0 = tk * 32, n0 = tn * 32;
        const int nin = tid & 31;
        const int r8  = tid >> 5;            // 0..7
        #pragma unroll
        for (int s = 0; s < 4; ++s) {
            int k = s * 8 + r8;
            tile[k][nin] = W1[(size_t)(k0 + k) * HIDD + n0 + nin];
        }
        __syncthreads();
        #pragma unroll
        for (int s = 0; s < 4; ++s) {
            int nn = s * 8 + r8;
            W1t[(size_t)(n0 + nn) * FIN + k0 + nin] = f2bf(tile[nin][nn]);
        }
    } else if (bid < PREP_TB2) {
        int local = (bid - PREP_TB1) * 256 + tid;   // 0..32767
        int nn = local >> 7;         // 0..255 output col
        int k  = local & 127;        // 0..127 input row
        float s = 0.f;
        #pragma unroll 8
        for (int t = 0; t < HIDD; ++t)
            s += W2[(size_t)k * OUTD + t] * Wg[(size_t)t * HC + nn];
        W2gt[(size_t)nn * HIDD + k] = f2bf(s);
        if (k == 0) {
            float t2 = 0.f;
            #pragma unroll 8
            for (int t = 0; t < OUTD; ++t) t2 += b2[t] * Wg[(size_t)t * HC + nn];
            b2g[nn] = t2;
        }
    } else {
        int i = (bid - PREP_TB2) * 256 + tid;
        if (i < n) deg[i] = 1;      // self loop
    }
}

// ---------------------------------------------------------------------------
// GEMM1 (+ fused degree count): h1 = relu(x @ W1t^T + b1)  [bf16 out]
//   BM=32, BN=128(=N), BK=64; 4 waves (2x2); XOR-swizzled LDS.
//   Blocks >= gemmBlocks do the edge-degree atomic count (overlapped).
// ---------------------------------------------------------------------------
__global__ __launch_bounds__(256)
void gemm1_count_kernel(const float* __restrict__ A,            // x [M][512] fp32
                        const unsigned short* __restrict__ Bt,  // W1t [128][512]
                        const float* __restrict__ bias,         // b1
                        unsigned short* __restrict__ C,         // h1 [M][128]
                        const int* __restrict__ dst, int* __restrict__ deg,
                        int M, int E, int gemmBlocks) {
    __shared__ unsigned short As[32 * 64];    // 4 KB
    __shared__ unsigned short Bs[128 * 64];   // 16 KB

    if ((int)blockIdx.x >= gemmBlocks) {
        int i = ((int)blockIdx.x - gemmBlocks) * 256 + threadIdx.x;
        if (i < E) atomicAdd(&deg[dst[i]], 1);
        return;
    }

    const int tid  = threadIdx.x;
    const int lane = tid & 63;
    const int w    = tid >> 6;
    const int wr   = w >> 1;
    const int wc   = w & 1;
    const int m0   = blockIdx.x * 32;

    char* pA = (char*)As;
    char* pB = (char*)Bs;

    f32x4 acc[4];
    #pragma unroll
    for (int n = 0; n < 4; ++n) acc[n] = (f32x4){0.f, 0.f, 0.f, 0.f};

    for (int k0 = 0; k0 < FIN; k0 += 64) {
        {
            const int row = tid >> 3;                // 0..31
            const int sg  = tid & 7;                 // 8-float segment
            const bool ok = (m0 + row) < M;
            const float4* Ap = (const float4*)(A + (size_t)(m0 + row) * FIN + k0 + sg * 8);
            float4 f0 = make_float4(0,0,0,0), f1 = f0;
            if (ok) { f0 = Ap[0]; f1 = Ap[1]; }
            unsigned short u[8];
            u[0]=f2bf(f0.x); u[1]=f2bf(f0.y); u[2]=f2bf(f0.z); u[3]=f2bf(f0.w);
            u[4]=f2bf(f1.x); u[5]=f2bf(f1.y); u[6]=f2bf(f1.z); u[7]=f2bf(f1.w);
            *(bf16x8*)(pA + (((row * 128 + sg * 16)) ^ ((row & 7) << 4))) = *(bf16x8*)&u[0];
        }
        #pragma unroll
        for (int i = 0; i < 4; ++i) {
            int s   = tid + i * 256;
            int col = s >> 3;
            int sg  = s & 7;
            bf16x8 v = *(const bf16x8*)(Bt + (size_t)col * FIN + k0 + sg * 8);
            *(bf16x8*)(pB + (((col * 128 + sg * 16)) ^ ((col & 7) << 4))) = v;
        }
        __syncthreads();

        #pragma unroll
        for (int ks = 0; ks < 2; ++ks) {
            const int kb = ks * 64 + ((lane >> 4) << 4);
            int row = wr * 16 + (lane & 15);
            bf16x8 a = *(const bf16x8*)(pA + ((row * 128 + kb) ^ ((row & 7) << 4)));
            bf16x8 b[4];
            #pragma unroll
            for (int n = 0; n < 4; ++n) {
                int col = wc * 64 + n * 16 + (lane & 15);
                b[n] = *(const bf16x8*)(pB + ((col * 128 + kb) ^ ((col & 7) << 4)));
            }
            #pragma unroll
            for (int n = 0; n < 4; ++n)
                acc[n] = __builtin_amdgcn_mfma_f32_16x16x32_bf16(a, b[n], acc[n], 0, 0, 0);
        }
        __syncthreads();
    }

    #pragma unroll
    for (int n = 0; n < 4; ++n) {
        const int col = wc * 64 + n * 16 + (lane & 15);
        const float bv = bias[col];
        #pragma unroll
        for (int r = 0; r < 4; ++r) {
            const int row = m0 + wr * 16 + ((lane >> 4) << 2) + r;
            if (row >= M) continue;
            float v = fmaxf(acc[n][r] + bv, 0.f);
            C[(size_t)row * HIDD + col] = f2bf(v);
        }
    }
}

// ---------------------------------------------------------------------------
// GEMM2 (+ fused attention dots): xgb = h1 @ W2gt^T + b2g  [bf16 out]
//   BM=64, BN=128, K=128; 4 waves (2x2). Each wave's 32x64 tile = one head's
//   channels -> per-thread FMA + 16-lane shfl reduce gives a_src/a_dst.
// ---------------------------------------------------------------------------
__global__ __launch_bounds__(256)
void gemm2_dots_kernel(const unsigned short* __restrict__ Ab,   // h1 [M][128] bf16
                       const unsigned short* __restrict__ Bt,   // W2gt [256][128] bf16
                       const float* __restrict__ b2g,           // [256]
                       const float* __restrict__ att_src,       // [4][64]
                       const float* __restrict__ att_dst,       // [4][64]
                       unsigned short* __restrict__ xgb,        // [M][256] bf16
                       float* __restrict__ a_src, float* __restrict__ a_dst,
                       int M) {
    __shared__ unsigned short As[64 * 64];    // 8 KB
    __shared__ unsigned short Bs[128 * 64];   // 16 KB

    const int tid  = threadIdx.x;
    const int lane = tid & 63;
    const int w    = tid >> 6;
    const int wr   = w >> 1;
    const int wc   = w & 1;
    const int m0   = blockIdx.x * 64;
    const int n0   = blockIdx.y * 128;

    char* pA = (char*)As;
    char* pB = (char*)Bs;

    f32x4 acc[2][4];
    #pragma unroll
    for (int m = 0; m < 2; ++m)
        #pragma unroll
        for (int n = 0; n < 4; ++n) acc[m][n] = (f32x4){0.f, 0.f, 0.f, 0.f};

    for (int k0 = 0; k0 < HIDD; k0 += 64) {
        #pragma unroll
        for (int i = 0; i < 2; ++i) {
            int s   = tid + i * 256;
            int row = s >> 3;
            int sg  = s & 7;
            bf16x8 v = {};
            if ((m0 + row) < M)
                v = *(const bf16x8*)(Ab + (size_t)(m0 + row) * HIDD + k0 + sg * 8);
            *(bf16x8*)(pA + (((row * 128 + sg * 16)) ^ ((row & 7) << 4))) = v;
        }
        #pragma unroll
        for (int i = 0; i < 4; ++i) {
            int s   = tid + i * 256;
            int col = s >> 3;
            int sg  = s & 7;
            bf16x8 v = *(const bf16x8*)(Bt + (size_t)(n0 + col) * HIDD + k0 + sg * 8);
            *(bf16x8*)(pB + (((col * 128 + sg * 16)) ^ ((col & 7) << 4))) = v;
        }
        __syncthreads();

        #pragma unroll
        for (int ks = 0; ks < 2; ++ks) {
            const int kb = ks * 64 + ((lane >> 4) << 4);
            bf16x8 a[2], b[4];
            #pragma unroll
            for (int m = 0; m < 2; ++m) {
                int row = wr * 32 + m * 16 + (lane & 15);
                a[m] = *(const bf16x8*)(pA + ((row * 128 + kb) ^ ((row & 7) << 4)));
            }
            #pragma unroll
            for (int n = 0; n < 4; ++n) {
                int col = wc * 64 + n * 16 + (lane & 15);
                b[n] = *(const bf16x8*)(pB + ((col * 128 + kb) ^ ((col & 7) << 4)));
            }
            #pragma unroll
            for (int m = 0; m < 2; ++m)
                #pragma unroll
                for (int n = 0; n < 4; ++n)
                    acc[m][n] = __builtin_amdgcn_mfma_f32_16x16x32_bf16(
                        a[m], b[n], acc[m][n], 0, 0, 0);
        }
        __syncthreads();
    }

    // ---- epilogue: store xgb + per-head attention dots ----
    const int head = blockIdx.y * 2 + wc;            // 0..3
    const int cIn  = lane & 15;
    float ds_p[2][4], dd_p[2][4];
    #pragma unroll
    for (int m = 0; m < 2; ++m)
        #pragma unroll
        for (int r = 0; r < 4; ++r) { ds_p[m][r] = 0.f; dd_p[m][r] = 0.f; }

    #pragma unroll
    for (int n = 0; n < 4; ++n) {
        const int ch  = n * 16 + cIn;                // channel within head
        const int col = n0 + wc * 64 + n * 16 + cIn;
        const float bv   = b2g[col];
        const float as_c = att_src[head * NC + ch];
        const float ad_c = att_dst[head * NC + ch];
        #pragma unroll
        for (int m = 0; m < 2; ++m) {
            #pragma unroll
            for (int r = 0; r < 4; ++r) {
                const int row = m0 + wr * 32 + m * 16 + ((lane >> 4) << 2) + r;
                float v = acc[m][n][r] + bv;
                if (row < M) xgb[(size_t)row * HC + col] = f2bf(v);
                ds_p[m][r] += v * as_c;
                dd_p[m][r] += v * ad_c;
            }
        }
    }
    #pragma unroll
    for (int m = 0; m < 2; ++m) {
        #pragma unroll
        for (int r = 0; r < 4; ++r) {
            float s = ds_p[m][r], d = dd_p[m][r];
            s += __shfl_xor(s, 1); s += __shfl_xor(s, 2);
            s += __shfl_xor(s, 4); s += __shfl_xor(s, 8);
            d += __shfl_xor(d, 1); d += __shfl_xor(d, 2);
            d += __shfl_xor(d, 4); d += __shfl_xor(d, 8);
            if (cIn == 0) {
                const int row = m0 + wr * 32 + m * 16 + ((lane >> 4) << 2) + r;
                if (row < M) {
                    a_src[row * NH + head] = s;
                    a_dst[row * NH + head] = d;
                }
            }
        }
    }
}

// ---------------------------------------------------------------------------
// Single-block scan, 1024 threads, 20 elems/thread in registers, 2 barriers.
// Also pre-places the self loop: csr[offs[i]] = i, cursor[i] = offs[i]+1.
// n <= 20480.
// ---------------------------------------------------------------------------
__global__ __launch_bounds__(1024)
void scan_offsets_kernel(const int* __restrict__ deg, int* __restrict__ offs,
                         int* __restrict__ cursor, int* __restrict__ csr, int n) {
    __shared__ int wsum[16], wbase[16];
    const int tid = threadIdx.x, lane = tid & 63, w = tid >> 6;
    const int i0 = tid * 20;
    int loc[20];
    int s = 0;
    #pragma unroll
    for (int k = 0; k < 20; ++k) {
        int i = i0 + k;
        int v = (i < n) ? deg[i] : 0;
        loc[k] = s;
        s += v;
    }
    int incl = s;
    #pragma unroll
    for (int d = 1; d < 64; d <<= 1) {
        int t = __shfl_up(incl, d);
        if (lane >= d) incl += t;
    }
    if (lane == 63) wsum[w] = incl;
    __syncthreads();
    if (w == 0) {
        int v = (lane < 16) ? wsum[lane] : 0;
        int sc = v;
        #pragma unroll
        for (int d = 1; d < 16; d <<= 1) {
            int t = __shfl_up(sc, d);
            if (lane >= d) sc += t;
        }
        if (lane < 16) wbase[lane] = sc - v;
    }
    __syncthreads();
    const int excl = wbase[w] + incl - s;
    #pragma unroll
    for (int k = 0; k < 20; ++k) {
        int i = i0 + k;
        if (i < n) {
            int o = excl + loc[k];
            offs[i]   = o;
            cursor[i] = o + 1;   // slot 0 reserved for the self loop
            csr[o]    = i;
        }
    }
    if (tid == 1023) offs[n] = excl + s;
}

// ---------------------------------------------------------------------------
// Scatter real edges into CSR slots (self-loops pre-placed by the scan)
// ---------------------------------------------------------------------------
__global__ void scatter_kernel(const int* __restrict__ src, const int* __restrict__ dst,
                               int* __restrict__ cursor, int* __restrict__ csr_src,
                               int e) {
    int i = blockIdx.x * 256 + threadIdx.x;
    if (i < e) {
        int s = src[i], d = dst[i];
        csr_src[atomicAdd(&cursor[d], 1)] = s;
    }
}

// ---------------------------------------------------------------------------
// Aggregation v4: one wave per node.
// Pass A: lane-parallel softmax; logits from asrc gather (L2-resident) +
//         wave-uniform adst; exp/src cached in LDS.
// Pass B: half-wave channel split; 16-edge unroll (8 gathers in flight/lane).
// ---------------------------------------------------------------------------
__global__ __launch_bounds__(256)
void gat_aggregate4_kernel(const unsigned short* __restrict__ xgb,
                           const float4* __restrict__ asrc4,
                           const float4* __restrict__ adst4,
                           const int* __restrict__ offs, const int* __restrict__ csr_src,
                           const float* __restrict__ bias, float* __restrict__ out, int n) {
    __shared__ float4 exbuf[4][64];
    __shared__ int    sbuf[4][64];
    const int wv   = threadIdx.x >> 6;
    const int lane = threadIdx.x & 63;
    const int node = blockIdx.x * 4 + wv;
    if (node >= n) return;
    const int beg = offs[node], end = offs[node + 1];
    const int deg = end - beg;
    const float4 adstv = adst4[node];

    // ---- pass A ----
    float4 m   = make_float4(-INFINITY, -INFINITY, -INFINITY, -INFINITY);
    float4 den = make_float4(0.f, 0.f, 0.f, 0.f);
    for (int c0 = 0; c0 < deg; c0 += 64) {
        int idx = beg + c0 + lane;
        bool ok = idx < end;
        int s = ok ? csr_src[idx] : 0;
        float4 e = make_float4(-INFINITY, -INFINITY, -INFINITY, -INFINITY);
        if (ok) {
            float4 a = asrc4[s];
            e = f4add(a, adstv);
            e.x = e.x > 0.f ? e.x : 0.2f * e.x;
            e.y = e.y > 0.f ? e.y : 0.2f * e.y;
            e.z = e.z > 0.f ? e.z : 0.2f * e.z;
            e.w = e.w > 0.f ? e.w : 0.2f * e.w;
        }
        float4 cm = e;
        #pragma unroll
        for (int dd = 32; dd >= 1; dd >>= 1) cm = f4max(cm, shflx4(cm, dd));
        float4 nm = f4max(m, cm);
        float4 ex = f4exp(f4sub(e, nm));      // masked lanes: exp(-inf)=0
        exbuf[wv][lane] = ex;
        sbuf[wv][lane]  = s;
        float4 cs = ex;
        #pragma unroll
        for (int dd = 32; dd >= 1; dd >>= 1) cs = f4add(cs, shflx4(cs, dd));
        den = f4add(f4mul(den, f4exp(f4sub(m, nm))), cs);
        m = nm;
    }

    const int hi = lane >> 5;
    const int ll = lane & 31;       // owns channels 8*ll .. 8*ll+7
    const int h  = ll >> 3;
    const float denh = (h == 0) ? den.x : (h == 1) ? den.y : (h == 2) ? den.z : den.w;
    const float inv = 1.f / (denh + 1e-16f);

    float4 acc0 = make_float4(0.f, 0.f, 0.f, 0.f);
    float4 acc1 = make_float4(0.f, 0.f, 0.f, 0.f);
    const float* exf = (const float*)&exbuf[wv][0];

    auto do_edge = [&](int jj) {
        int s = sbuf[wv][jj];
        float wgt = exf[jj * 4 + h];
        bf16x8 v = *(const bf16x8*)(xgb + (size_t)s * HC + ll * 8);
        acc0.x += wgt * b2f(v[0]); acc0.y += wgt * b2f(v[1]);
        acc0.z += wgt * b2f(v[2]); acc0.w += wgt * b2f(v[3]);
        acc1.x += wgt * b2f(v[4]); acc1.y += wgt * b2f(v[5]);
        acc1.z += wgt * b2f(v[6]); acc1.w += wgt * b2f(v[7]);
    };

    auto run_chunk = [&](int cn) {
        int j = 0;
        for (; j + 16 <= cn; j += 16) {
            int ss[8]; float ww[8]; bf16x8 vv[8];
            #pragma unroll
            for (int t = 0; t < 8; ++t) {
                int jj = j + 2 * t + hi;
                ss[t] = sbuf[wv][jj];
                ww[t] = exf[jj * 4 + h];
            }
            #pragma unroll
            for (int t = 0; t < 8; ++t)
                vv[t] = *(const bf16x8*)(xgb + (size_t)ss[t] * HC + ll * 8);
            #pragma unroll
            for (int t = 0; t < 8; ++t) {
                acc0.x += ww[t]*b2f(vv[t][0]); acc0.y += ww[t]*b2f(vv[t][1]);
                acc0.z += ww[t]*b2f(vv[t][2]); acc0.w += ww[t]*b2f(vv[t][3]);
                acc1.x += ww[t]*b2f(vv[t][4]); acc1.y += ww[t]*b2f(vv[t][5]);
                acc1.z += ww[t]*b2f(vv[t][6]); acc1.w += ww[t]*b2f(vv[t][7]);
            }
        }
        for (; j + 8 <= cn; j += 8) {
            do_edge(j + hi);     do_edge(j + 2 + hi);
            do_edge(j + 4 + hi); do_edge(j + 6 + hi);
        }
        for (; j + 4 <= cn; j += 4) {
            do_edge(j + hi);
            do_edge(j + 2 + hi);
        }
        for (; j < cn; j += 2) {
            int jj = j + hi;
            if (jj < cn) do_edge(jj);
        }
    };

    if (deg <= 64) {
        run_chunk(deg);
    } else {
        for (int c0 = 0; c0 < deg; c0 += 64) {
            int idx = beg + c0 + lane;
            if (idx < end) {
                int s = csr_src[idx];
                float4 e = f4add(asrc4[s], adstv);
                e.x = e.x > 0.f ? e.x : 0.2f * e.x;
                e.y = e.y > 0.f ? e.y : 0.2f * e.y;
                e.z = e.z > 0.f ? e.z : 0.2f * e.z;
                e.w = e.w > 0.f ? e.w : 0.2f * e.w;
                exbuf[wv][lane] = f4exp(f4sub(e, m));
                sbuf[wv][lane]  = s;
            }
            int cn = deg - c0; if (cn > 64) cn = 64;
            run_chunk(cn);
        }
    }

    // combine half-wave partials
    acc0.x += __shfl_xor(acc0.x, 32); acc0.y += __shfl_xor(acc0.y, 32);
    acc0.z += __shfl_xor(acc0.z, 32); acc0.w += __shfl_xor(acc0.w, 32);
    acc1.x += __shfl_xor(acc1.x, 32); acc1.y += __shfl_xor(acc1.y, 32);
    acc1.z += __shfl_xor(acc1.z, 32); acc1.w += __shfl_xor(acc1.w, 32);

    const float4* b4 = (const float4*)bias;
    float4* op = (float4*)(out + (size_t)node * HC);
    if (hi == 0) {
        float4 bv = b4[ll * 2];
        op[ll * 2] = make_float4(acc0.x * inv + bv.x, acc0.y * inv + bv.y,
                                 acc0.z * inv + bv.z, acc0.w * inv + bv.w);
    } else {
        float4 bv = b4[ll * 2 + 1];
        op[ll * 2 + 1] = make_float4(acc1.x * inv + bv.x, acc1.y * inv + bv.y,
                                     acc1.z * inv + bv.z, acc1.w * inv + bv.w);
    }
}

// ---------------------------------------------------------------------------
extern "C" void kernel_launch(void* const* d_in, const int* in_sizes, int n_in,
                              void* d_out, int out_size, void* d_ws, size_t ws_size,
                              hipStream_t stream) {
    const float* x       = (const float*)d_in[0];
    const int*   ei      = (const int*)d_in[1];
    const float* W1      = (const float*)d_in[2];
    const float* b1      = (const float*)d_in[3];
    const float* W2      = (const float*)d_in[4];
    const float* b2      = (const float*)d_in[5];
    const float* Wg      = (const float*)d_in[6];
    const float* att_src = (const float*)d_in[7];
    const float* att_dst = (const float*)d_in[8];
    const float* bias_g  = (const float*)d_in[9];

    const int Nn = in_sizes[0] / FIN;       // 20000
    const int E  = in_sizes[1] / 2;         // 320000
    const int* e_src = ei;
    const int* e_dst = ei + E;

    char* w = (char*)d_ws;
    auto alloc = [&](size_t bytes) { char* p = w; w += (bytes + 255) & ~(size_t)255; return p; };
    unsigned short* W1t  = (unsigned short*)alloc((size_t)OUTD * FIN * 2);
    unsigned short* W2gt = (unsigned short*)alloc((size_t)HC * HIDD * 2);
    float* b2g  = (float*)alloc(HC * 4);
    unsigned short* h1  = (unsigned short*)alloc((size_t)Nn * HIDD * 2);
    unsigned short* xgb = (unsigned short*)alloc((size_t)Nn * HC * 2);
    float* asrc = (float*)alloc((size_t)Nn * NH * 4);
    float* adst = (float*)alloc((size_t)Nn * NH * 4);
    int* deg    = (int*)alloc((size_t)Nn * 4);
    int* offs   = (int*)alloc((size_t)(Nn + 1) * 4);
    int* cursor = (int*)alloc((size_t)Nn * 4);
    int* csr    = (int*)alloc((size_t)(E + Nn) * 4);

    dim3 blk(256);

    // 1) prep: W1t transpose (LDS tiles) | W2gt+b2g | deg=1
    {
        int nb = PREP_TB2 + (Nn + 255) / 256;       // 64 + 128 + 79
        prep_kernel<<<dim3(nb), blk, 0, stream>>>(
            W1, W1t, W2, b2, Wg, W2gt, b2g, deg, Nn);
    }

    // 2) h1 = relu(x@W1 + b1)  [bf16]  + fused degree count
    {
        int gb = (Nn + 31) / 32;                 // 625 gemm blocks
        int cb = (E + 255) / 256;                // 1250 count blocks
        gemm1_count_kernel<<<dim3(gb + cb), blk, 0, stream>>>(
            x, W1t, b1, h1, e_dst, deg, Nn, E, gb);
    }

    // 3) xg = h1 @ W2g + b2g [bf16] + fused attention dots
    gemm2_dots_kernel<<<dim3((Nn + 63) / 64, 2), blk, 0, stream>>>(
        h1, W2gt, b2g, att_src, att_dst, xgb, asrc, adst, Nn);

    // 4) scan (dedicated single block — cheap, wide, register-resident)
    scan_offsets_kernel<<<dim3(1), dim3(1024), 0, stream>>>(deg, offs, cursor, csr, Nn);

    // 5) scatter real edges (self-loops already placed)
    scatter_kernel<<<dim3((E + 255) / 256), blk, 0, stream>>>(
        e_src, e_dst, cursor, csr, E);

    // 6) softmax + aggregation
    gat_aggregate4_kernel<<<dim3((Nn + 3) / 4), blk, 0, stream>>>(
        xgb, (const float4*)asrc, (const float4*)adst, offs, csr, bias_g,
        (float*)d_out, Nn);
}

// Round 8
// 130.978 us; speedup vs baseline: 1.1269x; 1.0370x over previous
//
#include <hip/hip_runtime.h>
#include <math.h>

// Problem constants (fixed by the reference)
#define NNODES 20000
#define NEDGES 320000
#define FIN    512
#define HIDD   128
#define OUTD   128
#define NH     4
#define NC     64
#define HC     256   // NH*NC

typedef short bf16x8 __attribute__((ext_vector_type(8)));
typedef float f32x4  __attribute__((ext_vector_type(4)));

__device__ __forceinline__ unsigned short f2bf(float f) {
    unsigned int u = __float_as_uint(f);
    unsigned int r = 0x7fffu + ((u >> 16) & 1u);
    return (unsigned short)((u + r) >> 16);
}
__device__ __forceinline__ float b2f(short t) {
    return __uint_as_float(((unsigned)(unsigned short)t) << 16);
}
__device__ __forceinline__ float4 f4max(float4 a, float4 b) {
    return make_float4(fmaxf(a.x,b.x), fmaxf(a.y,b.y), fmaxf(a.z,b.z), fmaxf(a.w,b.w));
}
__device__ __forceinline__ float4 f4add(float4 a, float4 b) {
    return make_float4(a.x+b.x, a.y+b.y, a.z+b.z, a.w+b.w);
}
__device__ __forceinline__ float4 f4sub(float4 a, float4 b) {
    return make_float4(a.x-b.x, a.y-b.y, a.z-b.z, a.w-b.w);
}
__device__ __forceinline__ float4 f4mul(float4 a, float4 b) {
    return make_float4(a.x*b.x, a.y*b.y, a.z*b.z, a.w*b.w);
}
__device__ __forceinline__ float4 f4exp(float4 a) {
    return make_float4(__expf(a.x), __expf(a.y), __expf(a.z), __expf(a.w));
}
__device__ __forceinline__ float4 shflx4(float4 v, int m) {
    return make_float4(__shfl_xor(v.x,m), __shfl_xor(v.y,m), __shfl_xor(v.z,m), __shfl_xor(v.w,m));
}

// ---------------------------------------------------------------------------
// Prep (role-split blocks):
//   blocks [0,64):    W1 transpose-cast via LDS tile (coalesced both sides)
//   blocks [64,192):  W2@Wg fuse -> W2gt bf16 + b2g
//   blocks [192,...): deg init (=1 self loop)
// ---------------------------------------------------------------------------
#define PREP_TB1 64
#define PREP_TB2 192
__global__ __launch_bounds__(256)
void prep_kernel(const float* __restrict__ W1, unsigned short* __restrict__ W1t,
                 const float* __restrict__ W2, const float* __restrict__ b2,
                 const float* __restrict__ Wg, unsigned short* __restrict__ W2gt,
                 float* __restrict__ b2g, int* __restrict__ deg, int n) {
    const int bid = blockIdx.x;
    const int tid = threadIdx.x;
    if (bid < PREP_TB1) {
        // 32x32 tile transpose: W1 [512][128] fp32 -> W1t [128][512] bf16
        __shared__ float tile[32][33];
        const int tk = bid >> 2;             // 0..15 (k tiles)
        const int tn = bid & 3;              // 0..3  (n tiles)
        const int k0 = tk * 32, n0 = tn * 32;
        const int nin = tid & 31;
        const int r8  = tid >> 5;            // 0..7
        #pragma unroll
        for (int s = 0; s < 4; ++s) {
            int k = s * 8 + r8;
            tile[k][nin] = W1[(size_t)(k0 + k) * HIDD + n0 + nin];
        }
        __syncthreads();
        #pragma unroll
        for (int s = 0; s < 4; ++s) {
            int nn = s * 8 + r8;
            W1t[(size_t)(n0 + nn) * FIN + k0 + nin] = f2bf(tile[nin][nn]);
        }
    } else if (bid < PREP_TB2) {
        int local = (bid - PREP_TB1) * 256 + tid;   // 0..32767
        int nn = local >> 7;         // 0..255 output col
        int k  = local & 127;        // 0..127 input row
        float s = 0.f;
        #pragma unroll 8
        for (int t = 0; t < HIDD; ++t)
            s += W2[(size_t)k * OUTD + t] * Wg[(size_t)t * HC + nn];
        W2gt[(size_t)nn * HIDD + k] = f2bf(s);
        if (k == 0) {
            float t2 = 0.f;
            #pragma unroll 8
            for (int t = 0; t < OUTD; ++t) t2 += b2[t] * Wg[(size_t)t * HC + nn];
            b2g[nn] = t2;
        }
    } else {
        int i = (bid - PREP_TB2) * 256 + tid;
        if (i < n) deg[i] = 1;      // self loop
    }
}

// ---------------------------------------------------------------------------
// GEMM1 (+ fused degree count): h1 = relu(x @ W1t^T + b1)  [bf16 out]
//   BM=32, BN=128(=N), BK=64; 4 waves (2x2); XOR-swizzled LDS.
//   Blocks >= gemmBlocks do the edge-degree atomic count (overlapped).
// ---------------------------------------------------------------------------
__global__ __launch_bounds__(256)
void gemm1_count_kernel(const float* __restrict__ A,            // x [M][512] fp32
                        const unsigned short* __restrict__ Bt,  // W1t [128][512]
                        const float* __restrict__ bias,         // b1
                        unsigned short* __restrict__ C,         // h1 [M][128]
                        const int* __restrict__ dst, int* __restrict__ deg,
                        int M, int E, int gemmBlocks) {
    __shared__ unsigned short As[32 * 64];    // 4 KB
    __shared__ unsigned short Bs[128 * 64];   // 16 KB

    if ((int)blockIdx.x >= gemmBlocks) {
        int i = ((int)blockIdx.x - gemmBlocks) * 256 + threadIdx.x;
        if (i < E) atomicAdd(&deg[dst[i]], 1);
        return;
    }

    const int tid  = threadIdx.x;
    const int lane = tid & 63;
    const int w    = tid >> 6;
    const int wr   = w >> 1;
    const int wc   = w & 1;
    const int m0   = blockIdx.x * 32;

    char* pA = (char*)As;
    char* pB = (char*)Bs;

    f32x4 acc[4];
    #pragma unroll
    for (int n = 0; n < 4; ++n) acc[n] = (f32x4){0.f, 0.f, 0.f, 0.f};

    for (int k0 = 0; k0 < FIN; k0 += 64) {
        {
            const int row = tid >> 3;                // 0..31
            const int sg  = tid & 7;                 // 8-float segment
            const bool ok = (m0 + row) < M;
            const float4* Ap = (const float4*)(A + (size_t)(m0 + row) * FIN + k0 + sg * 8);
            float4 f0 = make_float4(0,0,0,0), f1 = f0;
            if (ok) { f0 = Ap[0]; f1 = Ap[1]; }
            unsigned short u[8];
            u[0]=f2bf(f0.x); u[1]=f2bf(f0.y); u[2]=f2bf(f0.z); u[3]=f2bf(f0.w);
            u[4]=f2bf(f1.x); u[5]=f2bf(f1.y); u[6]=f2bf(f1.z); u[7]=f2bf(f1.w);
            *(bf16x8*)(pA + (((row * 128 + sg * 16)) ^ ((row & 7) << 4))) = *(bf16x8*)&u[0];
        }
        #pragma unroll
        for (int i = 0; i < 4; ++i) {
            int s   = tid + i * 256;
            int col = s >> 3;
            int sg  = s & 7;
            bf16x8 v = *(const bf16x8*)(Bt + (size_t)col * FIN + k0 + sg * 8);
            *(bf16x8*)(pB + (((col * 128 + sg * 16)) ^ ((col & 7) << 4))) = v;
        }
        __syncthreads();

        #pragma unroll
        for (int ks = 0; ks < 2; ++ks) {
            const int kb = ks * 64 + ((lane >> 4) << 4);
            int row = wr * 16 + (lane & 15);
            bf16x8 a = *(const bf16x8*)(pA + ((row * 128 + kb) ^ ((row & 7) << 4)));
            bf16x8 b[4];
            #pragma unroll
            for (int n = 0; n < 4; ++n) {
                int col = wc * 64 + n * 16 + (lane & 15);
                b[n] = *(const bf16x8*)(pB + ((col * 128 + kb) ^ ((col & 7) << 4)));
            }
            #pragma unroll
            for (int n = 0; n < 4; ++n)
                acc[n] = __builtin_amdgcn_mfma_f32_16x16x32_bf16(a, b[n], acc[n], 0, 0, 0);
        }
        __syncthreads();
    }

    #pragma unroll
    for (int n = 0; n < 4; ++n) {
        const int col = wc * 64 + n * 16 + (lane & 15);
        const float bv = bias[col];
        #pragma unroll
        for (int r = 0; r < 4; ++r) {
            const int row = m0 + wr * 16 + ((lane >> 4) << 2) + r;
            if (row >= M) continue;
            float v = fmaxf(acc[n][r] + bv, 0.f);
            C[(size_t)row * HIDD + col] = f2bf(v);
        }
    }
}

// ---------------------------------------------------------------------------
// Single-block scan, 1024 threads, 20 elems/thread in registers, 2 barriers.
// Also pre-places the self loop: csr[offs[i]] = i, cursor[i] = offs[i]+1.
// n <= 20480.
// ---------------------------------------------------------------------------
__global__ __launch_bounds__(1024)
void scan_offsets_kernel(const int* __restrict__ deg, int* __restrict__ offs,
                         int* __restrict__ cursor, int* __restrict__ csr, int n) {
    __shared__ int wsum[16], wbase[16];
    const int tid = threadIdx.x, lane = tid & 63, w = tid >> 6;
    const int i0 = tid * 20;
    int loc[20];
    int s = 0;
    #pragma unroll
    for (int k = 0; k < 20; ++k) {
        int i = i0 + k;
        int v = (i < n) ? deg[i] : 0;
        loc[k] = s;
        s += v;
    }
    int incl = s;
    #pragma unroll
    for (int d = 1; d < 64; d <<= 1) {
        int t = __shfl_up(incl, d);
        if (lane >= d) incl += t;
    }
    if (lane == 63) wsum[w] = incl;
    __syncthreads();
    if (w == 0) {
        int v = (lane < 16) ? wsum[lane] : 0;
        int sc = v;
        #pragma unroll
        for (int d = 1; d < 16; d <<= 1) {
            int t = __shfl_up(sc, d);
            if (lane >= d) sc += t;
        }
        if (lane < 16) wbase[lane] = sc - v;
    }
    __syncthreads();
    const int excl = wbase[w] + incl - s;
    #pragma unroll
    for (int k = 0; k < 20; ++k) {
        int i = i0 + k;
        if (i < n) {
            int o = excl + loc[k];
            offs[i]   = o;
            cursor[i] = o + 1;   // slot 0 reserved for the self loop
            csr[o]    = i;
        }
    }
    if (tid == 1023) offs[n] = excl + s;
}

// ---------------------------------------------------------------------------
// GEMM2 (+ fused attention dots + fused edge scatter):
//   blocks [0, gemmBlocks): xgb = h1 @ W2gt^T + b2g [bf16] with per-head
//     attention dots in the epilogue (bx=bid>>1 m-tile, by=bid&1 n-tile).
//   blocks [gemmBlocks, ...): scatter real edges into CSR slots (cursor/csr
//     are ready — scan ran before this kernel; no data overlap with gemm).
// ---------------------------------------------------------------------------
__global__ __launch_bounds__(256)
void gemm2_dots_scatter_kernel(const unsigned short* __restrict__ Ab,   // h1 [M][128]
                               const unsigned short* __restrict__ Bt,   // W2gt [256][128]
                               const float* __restrict__ b2g,           // [256]
                               const float* __restrict__ att_src,       // [4][64]
                               const float* __restrict__ att_dst,       // [4][64]
                               unsigned short* __restrict__ xgb,        // [M][256]
                               float* __restrict__ a_src, float* __restrict__ a_dst,
                               const int* __restrict__ e_src, const int* __restrict__ e_dst,
                               int* __restrict__ cursor, int* __restrict__ csr,
                               int M, int E, int gemmBlocks) {
    const int tid = threadIdx.x;

    if ((int)blockIdx.x >= gemmBlocks) {
        int i = ((int)blockIdx.x - gemmBlocks) * 256 + tid;
        if (i < E) {
            int s = e_src[i], d = e_dst[i];
            csr[atomicAdd(&cursor[d], 1)] = s;
        }
        return;
    }

    __shared__ unsigned short As[64 * 64];    // 8 KB
    __shared__ unsigned short Bs[128 * 64];   // 16 KB

    const int lane = tid & 63;
    const int w    = tid >> 6;
    const int wr   = w >> 1;
    const int wc   = w & 1;
    const int m0   = ((int)blockIdx.x >> 1) * 64;
    const int n0   = ((int)blockIdx.x & 1) * 128;

    char* pA = (char*)As;
    char* pB = (char*)Bs;

    f32x4 acc[2][4];
    #pragma unroll
    for (int m = 0; m < 2; ++m)
        #pragma unroll
        for (int n = 0; n < 4; ++n) acc[m][n] = (f32x4){0.f, 0.f, 0.f, 0.f};

    for (int k0 = 0; k0 < HIDD; k0 += 64) {
        #pragma unroll
        for (int i = 0; i < 2; ++i) {
            int s   = tid + i * 256;
            int row = s >> 3;
            int sg  = s & 7;
            bf16x8 v = {};
            if ((m0 + row) < M)
                v = *(const bf16x8*)(Ab + (size_t)(m0 + row) * HIDD + k0 + sg * 8);
            *(bf16x8*)(pA + (((row * 128 + sg * 16)) ^ ((row & 7) << 4))) = v;
        }
        #pragma unroll
        for (int i = 0; i < 4; ++i) {
            int s   = tid + i * 256;
            int col = s >> 3;
            int sg  = s & 7;
            bf16x8 v = *(const bf16x8*)(Bt + (size_t)(n0 + col) * HIDD + k0 + sg * 8);
            *(bf16x8*)(pB + (((col * 128 + sg * 16)) ^ ((col & 7) << 4))) = v;
        }
        __syncthreads();

        #pragma unroll
        for (int ks = 0; ks < 2; ++ks) {
            const int kb = ks * 64 + ((lane >> 4) << 4);
            bf16x8 a[2], b[4];
            #pragma unroll
            for (int m = 0; m < 2; ++m) {
                int row = wr * 32 + m * 16 + (lane & 15);
                a[m] = *(const bf16x8*)(pA + ((row * 128 + kb) ^ ((row & 7) << 4)));
            }
            #pragma unroll
            for (int n = 0; n < 4; ++n) {
                int col = wc * 64 + n * 16 + (lane & 15);
                b[n] = *(const bf16x8*)(pB + ((col * 128 + kb) ^ ((col & 7) << 4)));
            }
            #pragma unroll
            for (int m = 0; m < 2; ++m)
                #pragma unroll
                for (int n = 0; n < 4; ++n)
                    acc[m][n] = __builtin_amdgcn_mfma_f32_16x16x32_bf16(
                        a[m], b[n], acc[m][n], 0, 0, 0);
        }
        __syncthreads();
    }

    // ---- epilogue: store xgb + per-head attention dots ----
    const int head = ((int)blockIdx.x & 1) * 2 + wc;     // 0..3
    const int cIn  = lane & 15;
    float ds_p[2][4], dd_p[2][4];
    #pragma unroll
    for (int m = 0; m < 2; ++m)
        #pragma unroll
        for (int r = 0; r < 4; ++r) { ds_p[m][r] = 0.f; dd_p[m][r] = 0.f; }

    #pragma unroll
    for (int n = 0; n < 4; ++n) {
        const int ch  = n * 16 + cIn;                // channel within head
        const int col = n0 + wc * 64 + n * 16 + cIn;
        const float bv   = b2g[col];
        const float as_c = att_src[head * NC + ch];
        const float ad_c = att_dst[head * NC + ch];
        #pragma unroll
        for (int m = 0; m < 2; ++m) {
            #pragma unroll
            for (int r = 0; r < 4; ++r) {
                const int row = m0 + wr * 32 + m * 16 + ((lane >> 4) << 2) + r;
                float v = acc[m][n][r] + bv;
                if (row < M) xgb[(size_t)row * HC + col] = f2bf(v);
                ds_p[m][r] += v * as_c;
                dd_p[m][r] += v * ad_c;
            }
        }
    }
    #pragma unroll
    for (int m = 0; m < 2; ++m) {
        #pragma unroll
        for (int r = 0; r < 4; ++r) {
            float s = ds_p[m][r], d = dd_p[m][r];
            s += __shfl_xor(s, 1); s += __shfl_xor(s, 2);
            s += __shfl_xor(s, 4); s += __shfl_xor(s, 8);
            d += __shfl_xor(d, 1); d += __shfl_xor(d, 2);
            d += __shfl_xor(d, 4); d += __shfl_xor(d, 8);
            if (cIn == 0) {
                const int row = m0 + wr * 32 + m * 16 + ((lane >> 4) << 2) + r;
                if (row < M) {
                    a_src[row * NH + head] = s;
                    a_dst[row * NH + head] = d;
                }
            }
        }
    }
}

// ---------------------------------------------------------------------------
// Aggregation v4: one wave per node.
// Pass A: lane-parallel softmax; logits from asrc gather (L2-resident) +
//         wave-uniform adst; exp/src cached in LDS.
// Pass B: half-wave channel split; 16-edge unroll (8 gathers in flight/lane).
// ---------------------------------------------------------------------------
__global__ __launch_bounds__(256)
void gat_aggregate4_kernel(const unsigned short* __restrict__ xgb,
                           const float4* __restrict__ asrc4,
                           const float4* __restrict__ adst4,
                           const int* __restrict__ offs, const int* __restrict__ csr_src,
                           const float* __restrict__ bias, float* __restrict__ out, int n) {
    __shared__ float4 exbuf[4][64];
    __shared__ int    sbuf[4][64];
    const int wv   = threadIdx.x >> 6;
    const int lane = threadIdx.x & 63;
    const int node = blockIdx.x * 4 + wv;
    if (node >= n) return;
    const int beg = offs[node], end = offs[node + 1];
    const int deg = end - beg;
    const float4 adstv = adst4[node];

    // ---- pass A ----
    float4 m   = make_float4(-INFINITY, -INFINITY, -INFINITY, -INFINITY);
    float4 den = make_float4(0.f, 0.f, 0.f, 0.f);
    for (int c0 = 0; c0 < deg; c0 += 64) {
        int idx = beg + c0 + lane;
        bool ok = idx < end;
        int s = ok ? csr_src[idx] : 0;
        float4 e = make_float4(-INFINITY, -INFINITY, -INFINITY, -INFINITY);
        if (ok) {
            float4 a = asrc4[s];
            e = f4add(a, adstv);
            e.x = e.x > 0.f ? e.x : 0.2f * e.x;
            e.y = e.y > 0.f ? e.y : 0.2f * e.y;
            e.z = e.z > 0.f ? e.z : 0.2f * e.z;
            e.w = e.w > 0.f ? e.w : 0.2f * e.w;
        }
        float4 cm = e;
        #pragma unroll
        for (int dd = 32; dd >= 1; dd >>= 1) cm = f4max(cm, shflx4(cm, dd));
        float4 nm = f4max(m, cm);
        float4 ex = f4exp(f4sub(e, nm));      // masked lanes: exp(-inf)=0
        exbuf[wv][lane] = ex;
        sbuf[wv][lane]  = s;
        float4 cs = ex;
        #pragma unroll
        for (int dd = 32; dd >= 1; dd >>= 1) cs = f4add(cs, shflx4(cs, dd));
        den = f4add(f4mul(den, f4exp(f4sub(m, nm))), cs);
        m = nm;
    }

    const int hi = lane >> 5;
    const int ll = lane & 31;       // owns channels 8*ll .. 8*ll+7
    const int h  = ll >> 3;
    const float denh = (h == 0) ? den.x : (h == 1) ? den.y : (h == 2) ? den.z : den.w;
    const float inv = 1.f / (denh + 1e-16f);

    float4 acc0 = make_float4(0.f, 0.f, 0.f, 0.f);
    float4 acc1 = make_float4(0.f, 0.f, 0.f, 0.f);
    const float* exf = (const float*)&exbuf[wv][0];

    auto do_edge = [&](int jj) {
        int s = sbuf[wv][jj];
        float wgt = exf[jj * 4 + h];
        bf16x8 v = *(const bf16x8*)(xgb + (size_t)s * HC + ll * 8);
        acc0.x += wgt * b2f(v[0]); acc0.y += wgt * b2f(v[1]);
        acc0.z += wgt * b2f(v[2]); acc0.w += wgt * b2f(v[3]);
        acc1.x += wgt * b2f(v[4]); acc1.y += wgt * b2f(v[5]);
        acc1.z += wgt * b2f(v[6]); acc1.w += wgt * b2f(v[7]);
    };

    auto run_chunk = [&](int cn) {
        int j = 0;
        for (; j + 16 <= cn; j += 16) {
            int ss[8]; float ww[8]; bf16x8 vv[8];
            #pragma unroll
            for (int t = 0; t < 8; ++t) {
                int jj = j + 2 * t + hi;
                ss[t] = sbuf[wv][jj];
                ww[t] = exf[jj * 4 + h];
            }
            #pragma unroll
            for (int t = 0; t < 8; ++t)
                vv[t] = *(const bf16x8*)(xgb + (size_t)ss[t] * HC + ll * 8);
            #pragma unroll
            for (int t = 0; t < 8; ++t) {
                acc0.x += ww[t]*b2f(vv[t][0]); acc0.y += ww[t]*b2f(vv[t][1]);
                acc0.z += ww[t]*b2f(vv[t][2]); acc0.w += ww[t]*b2f(vv[t][3]);
                acc1.x += ww[t]*b2f(vv[t][4]); acc1.y += ww[t]*b2f(vv[t][5]);
                acc1.z += ww[t]*b2f(vv[t][6]); acc1.w += ww[t]*b2f(vv[t][7]);
            }
        }
        for (; j + 8 <= cn; j += 8) {
            do_edge(j + hi);     do_edge(j + 2 + hi);
            do_edge(j + 4 + hi); do_edge(j + 6 + hi);
        }
        for (; j + 4 <= cn; j += 4) {
            do_edge(j + hi);
            do_edge(j + 2 + hi);
        }
        for (; j < cn; j += 2) {
            int jj = j + hi;
            if (jj < cn) do_edge(jj);
        }
    };

    if (deg <= 64) {
        run_chunk(deg);
    } else {
        for (int c0 = 0; c0 < deg; c0 += 64) {
            int idx = beg + c0 + lane;
            if (idx < end) {
                int s = csr_src[idx];
                float4 e = f4add(asrc4[s], adstv);
                e.x = e.x > 0.f ? e.x : 0.2f * e.x;
                e.y = e.y > 0.f ? e.y : 0.2f * e.y;
                e.z = e.z > 0.f ? e.z : 0.2f * e.z;
                e.w = e.w > 0.f ? e.w : 0.2f * e.w;
                exbuf[wv][lane] = f4exp(f4sub(e, m));
                sbuf[wv][lane]  = s;
            }
            int cn = deg - c0; if (cn > 64) cn = 64;
            run_chunk(cn);
        }
    }

    // combine half-wave partials
    acc0.x += __shfl_xor(acc0.x, 32); acc0.y += __shfl_xor(acc0.y, 32);
    acc0.z += __shfl_xor(acc0.z, 32); acc0.w += __shfl_xor(acc0.w, 32);
    acc1.x += __shfl_xor(acc1.x, 32); acc1.y += __shfl_xor(acc1.y, 32);
    acc1.z += __shfl_xor(acc1.z, 32); acc1.w += __shfl_xor(acc1.w, 32);

    const float4* b4 = (const float4*)bias;
    float4* op = (float4*)(out + (size_t)node * HC);
    if (hi == 0) {
        float4 bv = b4[ll * 2];
        op[ll * 2] = make_float4(acc0.x * inv + bv.x, acc0.y * inv + bv.y,
                                 acc0.z * inv + bv.z, acc0.w * inv + bv.w);
    } else {
        float4 bv = b4[ll * 2 + 1];
        op[ll * 2 + 1] = make_float4(acc1.x * inv + bv.x, acc1.y * inv + bv.y,
                                     acc1.z * inv + bv.z, acc1.w * inv + bv.w);
    }
}

// ---------------------------------------------------------------------------
extern "C" void kernel_launch(void* const* d_in, const int* in_sizes, int n_in,
                              void* d_out, int out_size, void* d_ws, size_t ws_size,
                              hipStream_t stream) {
    const float* x       = (const float*)d_in[0];
    const int*   ei      = (const int*)d_in[1];
    const float* W1      = (const float*)d_in[2];
    const float* b1      = (const float*)d_in[3];
    const float* W2      = (const float*)d_in[4];
    const float* b2      = (const float*)d_in[5];
    const float* Wg      = (const float*)d_in[6];
    const float* att_src = (const float*)d_in[7];
    const float* att_dst = (const float*)d_in[8];
    const float* bias_g  = (const float*)d_in[9];

    const int Nn = in_sizes[0] / FIN;       // 20000
    const int E  = in_sizes[1] / 2;         // 320000
    const int* e_src = ei;
    const int* e_dst = ei + E;

    char* w = (char*)d_ws;
    auto alloc = [&](size_t bytes) { char* p = w; w += (bytes + 255) & ~(size_t)255; return p; };
    unsigned short* W1t  = (unsigned short*)alloc((size_t)OUTD * FIN * 2);
    unsigned short* W2gt = (unsigned short*)alloc((size_t)HC * HIDD * 2);
    float* b2g  = (float*)alloc(HC * 4);
    unsigned short* h1  = (unsigned short*)alloc((size_t)Nn * HIDD * 2);
    unsigned short* xgb = (unsigned short*)alloc((size_t)Nn * HC * 2);
    float* asrc = (float*)alloc((size_t)Nn * NH * 4);
    float* adst = (float*)alloc((size_t)Nn * NH * 4);
    int* deg    = (int*)alloc((size_t)Nn * 4);
    int* offs   = (int*)alloc((size_t)(Nn + 1) * 4);
    int* cursor = (int*)alloc((size_t)Nn * 4);
    int* csr    = (int*)alloc((size_t)(E + Nn) * 4);

    dim3 blk(256);

    // 1) prep: W1t transpose (LDS tiles) | W2gt+b2g | deg=1
    {
        int nb = PREP_TB2 + (Nn + 255) / 256;       // 64 + 128 + 79
        prep_kernel<<<dim3(nb), blk, 0, stream>>>(
            W1, W1t, W2, b2, Wg, W2gt, b2g, deg, Nn);
    }

    // 2) h1 = relu(x@W1 + b1)  [bf16]  + fused degree count
    {
        int gb = (Nn + 31) / 32;                 // 625 gemm blocks
        int cb = (E + 255) / 256;                // 1250 count blocks
        gemm1_count_kernel<<<dim3(gb + cb), blk, 0, stream>>>(
            x, W1t, b1, h1, e_dst, deg, Nn, E, gb);
    }

    // 3) scan (dedicated single block — cheap, register-resident) + self-loops
    scan_offsets_kernel<<<dim3(1), dim3(1024), 0, stream>>>(deg, offs, cursor, csr, Nn);

    // 4) xg = h1 @ W2g + b2g [bf16] + dots + fused edge scatter (independent work)
    {
        int gb = ((Nn + 63) / 64) * 2;           // 626 gemm blocks (1D-encoded 2D)
        int sb = (E + 255) / 256;                // 1250 scatter blocks
        gemm2_dots_scatter_kernel<<<dim3(gb + sb), blk, 0, stream>>>(
            h1, W2gt, b2g, att_src, att_dst, xgb, asrc, adst,
            e_src, e_dst, cursor, csr, Nn, E, gb);
    }

    // 5) softmax + aggregation
    gat_aggregate4_kernel<<<dim3((Nn + 3) / 4), blk, 0, stream>>>(
        xgb, (const float4*)asrc, (const float4*)adst, offs, csr, bias_g,
        (float*)d_out, Nn);
}